// Round 9
// baseline (494.301 us; speedup 1.0000x reference)
//
#include <hip/hip_runtime.h>
#include <hip/hip_bf16.h>
#include <math.h>

#define B 64
#define NP 32
#define NS 72
#define NH 4
#define NF 64
#define HD 256
#define CTXD 112
#define NL 4
#define NC 110
#define LN_EPS 1e-6f
#define GROWS 8

// LDS strides for gat
#define SH 68   // hl_s / hr_s row stride (floats)
#define SA 76   // attnT row stride
#define SLN 264 // bf16 LDS row stride for MFMA A tiles (528B: 2-way banks on b128)

typedef __hip_bfloat16 bf16;
typedef unsigned short u16;
typedef float f32x4 __attribute__((ext_vector_type(4)));
typedef __bf16 bf16x8 __attribute__((ext_vector_type(8)));

__device__ __forceinline__ float ldv(const float* p, int i) { return p[i]; }
__device__ __forceinline__ float ldv(const bf16* p, int i) { return __bfloat162float(p[i]); }
__device__ __forceinline__ void stv(float* p, int i, float v) { p[i] = v; }
__device__ __forceinline__ void stv(bf16* p, int i, float v) { p[i] = __float2bfloat16(v); }
__device__ __forceinline__ u16 f2b(float f) {
  union { bf16 h; u16 u; } cv; cv.h = __float2bfloat16(f); return cv.u;
}
__device__ __forceinline__ float b2f(u16 u) { return __uint_as_float((unsigned)u << 16); }

// ---------- dtype detector: adj[0,0]==1.0 guaranteed (self-loop).
__global__ void k_detect(const void* adj, int* flag) {
  if (threadIdx.x == 0 && blockIdx.x == 0) {
    *flag = (((const u16*)adj)[0] == 0x3F80u) ? 1 : 0;
  }
}

// ---------- one-time weight transpose (bf16-input mode): W[l][k][n] -> Wt[l][n][k]
__global__ void __launch_bounds__(256) k_prep(const void* Wl, const void* Wr, const void* opW,
    const void* cpW, u16* Wlt, u16* Wrt, u16* opWt, u16* cpWt, const int* flag) {
  if (!*flag) return;
  __shared__ __align__(16) u16 tile[64][72];
  int bid = blockIdx.x, t = threadIdx.x;
  int tensor = bid >> 6, layer = (bid >> 4) & 3, ti = (bid >> 2) & 3, tj = bid & 3;
  const u16* srcs[4] = {(const u16*)Wl, (const u16*)Wr, (const u16*)opW, (const u16*)cpW};
  u16* dsts[4] = {Wlt, Wrt, opWt, cpWt};
  const u16* src = srcs[tensor] + (size_t)layer * HD * HD + (ti * 64) * HD + tj * 64;
  u16* dst = dsts[tensor] + (size_t)layer * HD * HD + (tj * 64) * HD + ti * 64;
  int r = t >> 2, cq = (t & 3) * 16;
  *(uint4*)&tile[r][cq]     = *(const uint4*)(src + r * HD + cq);
  *(uint4*)&tile[r][cq + 8] = *(const uint4*)(src + r * HD + cq + 8);
  __syncthreads();
  unsigned u[8];
  #pragma unroll
  for (int i = 0; i < 8; ++i)
    u[i] = (unsigned)tile[cq + 2 * i][r] | ((unsigned)tile[cq + 2 * i + 1][r] << 16);
  *(uint4*)(dst + r * HD + cq) = make_uint4(u[0], u[1], u[2], u[3]);
  *(uint4*)(dst + r * HD + cq + 8) = make_uint4(u[4], u[5], u[6], u[7]);
}

// ---------- one-time fp32 weight transpose+split (fp32-input mode, ws-permitting):
// W[l][k][n] fp32 -> Whi[l][n][k], Wlo[l][n][k] bf16 (Ootomo hi/lo split).
__global__ void __launch_bounds__(256) k_prep32(const void* Wl, const void* Wr, const void* opW,
    u16* WlHi, u16* WlLo, u16* WrHi, u16* WrLo, u16* opHi, u16* opLo, const int* flag) {
  if (*flag) return;  // fp32 mode only
  __shared__ float tile[64][65];
  int bid = blockIdx.x, t = threadIdx.x;
  int tensor = bid >> 6, layer = (bid >> 4) & 3, ti = (bid >> 2) & 3, tj = bid & 3;
  const float* srcs[3] = {(const float*)Wl, (const float*)Wr, (const float*)opW};
  const float* src = srcs[tensor] + (size_t)layer * HD * HD + (ti * 64) * HD + tj * 64;
  int r = t >> 2, cq = (t & 3) * 16;
  #pragma unroll
  for (int q = 0; q < 4; ++q) {
    float4 f4 = *(const float4*)(src + r * HD + cq + 4 * q);
    tile[r][cq + 4 * q]     = f4.x; tile[r][cq + 4 * q + 1] = f4.y;
    tile[r][cq + 4 * q + 2] = f4.z; tile[r][cq + 4 * q + 3] = f4.w;
  }
  __syncthreads();
  u16* Hs[3] = {WlHi, WrHi, opHi};
  u16* Ls[3] = {WlLo, WrLo, opLo};
  u16* dstH = Hs[tensor] + (size_t)layer * HD * HD + (tj * 64) * HD + ti * 64;
  u16* dstL = Ls[tensor] + (size_t)layer * HD * HD + (tj * 64) * HD + ti * 64;
  u16 hb[16], lb[16];
  #pragma unroll
  for (int i = 0; i < 16; ++i) {
    float wv = tile[cq + i][r];
    u16 hi = f2b(wv);
    hb[i] = hi;
    lb[i] = f2b(wv - b2f(hi));
  }
  unsigned uh[8], ul[8];
  #pragma unroll
  for (int i = 0; i < 8; ++i) {
    uh[i] = (unsigned)hb[2 * i] | ((unsigned)hb[2 * i + 1] << 16);
    ul[i] = (unsigned)lb[2 * i] | ((unsigned)lb[2 * i + 1] << 16);
  }
  *(uint4*)(dstH + r * HD + cq)     = make_uint4(uh[0], uh[1], uh[2], uh[3]);
  *(uint4*)(dstH + r * HD + cq + 8) = make_uint4(uh[4], uh[5], uh[6], uh[7]);
  *(uint4*)(dstL + r * HD + cq)     = make_uint4(ul[0], ul[1], ul[2], ul[3]);
  *(uint4*)(dstL + r * HD + cq + 8) = make_uint4(ul[4], ul[5], ul[6], ul[7]);
}

__device__ __forceinline__ void block_reduce_2(float& a, float& b, float* sred, int t) {
  #pragma unroll
  for (int o = 32; o > 0; o >>= 1) { a += __shfl_down(a, o); b += __shfl_down(b, o); }
  if ((t & 63) == 0) { sred[(t >> 6) * 2] = a; sred[(t >> 6) * 2 + 1] = b; }
  __syncthreads();
  a = sred[0] + sred[2] + sred[4] + sred[6];
  b = sred[1] + sred[3] + sred[5] + sred[7];
}

// ---------- shared MFMA cores: one 16(row)x64(col) C-quadrant per wave over K=256.
// A and B fragments use the SAME k-slot order -> contraction correct for any HW k-map.
__device__ __forceinline__ void mfma_accum(const u16* __restrict__ arow,
                                           const u16* __restrict__ brow, f32x4* acc) {
  #pragma unroll
  for (int kk = 0; kk < 8; ++kk) {
    bf16x8 a = *(const bf16x8*)(arow + kk * 32);
    #pragma unroll
    for (int f = 0; f < 4; ++f) {
      bf16x8 bv = *(const bf16x8*)(brow + (size_t)f * 16 * HD + kk * 32);
      acc[f] = __builtin_amdgcn_mfma_f32_16x16x32_bf16(a, bv, acc[f], 0, 0, 0);
    }
  }
}
// bf16x3 (Ootomo): acc += Ahi*Bhi + Ahi*Blo + Alo*Bhi  (Alo*Blo ~ 2^-18, dropped)
__device__ __forceinline__ void mfma3_accum(const u16* __restrict__ ahi, const u16* __restrict__ alo,
                                            const u16* __restrict__ bhi, const u16* __restrict__ blo,
                                            f32x4* acc) {
  #pragma unroll
  for (int kk = 0; kk < 8; ++kk) {
    bf16x8 ah = *(const bf16x8*)(ahi + kk * 32);
    bf16x8 al = *(const bf16x8*)(alo + kk * 32);
    #pragma unroll
    for (int f = 0; f < 4; ++f) {
      bf16x8 bh = *(const bf16x8*)(bhi + (size_t)f * 16 * HD + kk * 32);
      bf16x8 bl = *(const bf16x8*)(blo + (size_t)f * 16 * HD + kk * 32);
      acc[f] = __builtin_amdgcn_mfma_f32_16x16x32_bf16(al, bh, acc[f], 0, 0, 0);
      acc[f] = __builtin_amdgcn_mfma_f32_16x16x32_bf16(ah, bl, acc[f], 0, 0, 0);
      acc[f] = __builtin_amdgcn_mfma_f32_16x16x32_bf16(ah, bh, acc[f], 0, 0, 0);
    }
  }
}

// ---------- context head: g = relu(LN(ctx @ ctx_W + ctx_b)); also bf16 copy for bf16-MFMA path
template <typename T>
__device__ void ctx_body(const T* cardctx, const T* ctxW, const T* ctxb,
                         const T* lncs, const T* lncb, float* g, u16* gb,
                         float* sred, float* sctx) {
  int b = blockIdx.x, t = threadIdx.x;
  if (t < CTXD) sctx[t] = ldv(cardctx, b * CTXD + t);
  __syncthreads();
  float acc = ldv(ctxb, t);
  for (int k = 0; k < CTXD; ++k) acc += sctx[k] * ldv(ctxW, k * HD + t);
  float a = acc, bb = acc * acc;
  block_reduce_2(a, bb, sred, t);
  float mean = a * (1.f / HD);
  float var = bb * (1.f / HD) - mean * mean;
  float r = rsqrtf(var + LN_EPS);
  float v = (acc - mean) * r * ldv(lncs, t) + ldv(lncb, t);
  float rv = fmaxf(v, 0.f);
  g[b * HD + t] = rv;
  if (gb) gb[b * HD + t] = f2b(rv);
}
__global__ void __launch_bounds__(256) k_ctx(const void* cardctx, const void* ctxW, const void* ctxb,
    const void* lncs, const void* lncb, float* g, u16* gb, const int* flag) {
  __shared__ float sred[8];
  __shared__ float sctx[CTXD];
  if (*flag) ctx_body<bf16>((const bf16*)cardctx, (const bf16*)ctxW, (const bf16*)ctxb,
                            (const bf16*)lncs, (const bf16*)lncb, g, gb, sred, sctx);
  else ctx_body<float>((const float*)cardctx, (const float*)ctxW, (const float*)ctxb,
                       (const float*)lncs, (const float*)lncb, g, (u16*)0, sred, sctx);
}

// ---------- input projection
template <typename T>
__device__ void inproj_body(const T* spat, const T* inW, const T* inb, float* x, float* ssp) {
  int blk = blockIdx.x; int b = blk / NS; int s = blk % NS; int t = threadIdx.x;
  if (t < NP) ssp[t] = ldv(spat, (b * NP + t) * NS + s);
  __syncthreads();
  float acc = ldv(inb, t);
  #pragma unroll 8
  for (int p = 0; p < NP; ++p) acc += ssp[p] * ldv(inW, p * HD + t);
  x[blk * HD + t] = acc;
}
__global__ void __launch_bounds__(256) k_inproj(const void* spat, const void* inW, const void* inb,
                         float* x, const int* flag) {
  __shared__ float ssp[NP];
  if (*flag) inproj_body<bf16>((const bf16*)spat, (const bf16*)inW, (const bf16*)inb, x, ssp);
  else inproj_body<float>((const float*)spat, (const float*)inW, (const float*)inb, x, ssp);
}

// ---------- context projections, all 4 layers at once (layer-invariant -> hoisted)
__device__ void cproj_scalar(const float* g, const float* cpW, const float* cpb,
                             float* c_all, int l, int b, float* sg) {
  int t = threadIdx.x;
  sg[t] = g[b * HD + t];
  __syncthreads();
  const float* W = cpW + (size_t)l * HD * HD;
  float acc = cpb[l * HD + t];
  for (int k = 0; k < HD; ++k) acc += sg[k] * W[k * HD + t];
  c_all[((size_t)l * B + b) * HD + t] = acc;
}
__device__ void cproj_mfma(const u16* g_b, const u16* cpWt, const u16* cpb,
                           float* c_all, int l, int row0) {
  int t = threadIdx.x, w = t >> 6, ln = t & 63;
  int lr16 = ln & 15, lk = ln >> 4, c0 = w * 64;
  f32x4 acc[4] = {};
  const u16* arow = g_b + (size_t)(row0 + lr16) * HD + lk * 8;
  const u16* brow = cpWt + (size_t)l * HD * HD + (size_t)(c0 + lr16) * HD + lk * 8;
  mfma_accum(arow, brow, acc);
  int orow = row0 + lk * 4, ncol = c0 + lr16;
  #pragma unroll
  for (int f = 0; f < 4; ++f) {
    float bias = b2f(cpb[l * HD + ncol + f * 16]);
    #pragma unroll
    for (int j = 0; j < 4; ++j)
      c_all[((size_t)l * B + orow + j) * HD + ncol + f * 16] = acc[f][j] + bias;
  }
}
__global__ void __launch_bounds__(256) k_cproj_all(const float* g, const u16* g_b,
    const void* cpW, const u16* cpWt, const void* cpb, float* c_all, const int* flag) {
  __shared__ float sg[HD];
  if (*flag) {
    if (blockIdx.x < 16)
      cproj_mfma(g_b, cpWt, (const u16*)cpb, c_all, blockIdx.x >> 2, (blockIdx.x & 3) * 16);
  } else {
    cproj_scalar(g, (const float*)cpW, (const float*)cpb, c_all, blockIdx.x >> 6, blockIdx.x & 63, sg);
  }
}

// ---------- fused LN + dual GEMM: hl = (LN(x)+c) @ Wl, hr = (LN(x)+c) @ Wr
// v2: ONE block per 16-row tile does BOTH matrices (LN + bf16 staging was previously
// duplicated across the mat=0/mat=1 blocks; now staged once, 2 MFMA passes).
__device__ __forceinline__ void lngemm_mfma(const float* __restrict__ x, const float* __restrict__ c_all,
    const u16* __restrict__ lnps, const u16* __restrict__ lnpb,
    const u16* __restrict__ WtL, const u16* __restrict__ WtR,
    float* __restrict__ hl, float* __restrict__ hr, int l, int row0, u16* xs_b) {
  int t = threadIdx.x;
  int r = t >> 4, seg = t & 15;
  int grow = row0 + r, bb = grow / NS;
  const float* xrow = x + (size_t)grow * HD + seg * 16;
  float v[16]; float s = 0.f, s2 = 0.f;
  #pragma unroll
  for (int q = 0; q < 4; ++q) {
    float4 f4 = *(const float4*)(xrow + 4 * q);
    v[4 * q] = f4.x; v[4 * q + 1] = f4.y; v[4 * q + 2] = f4.z; v[4 * q + 3] = f4.w;
  }
  #pragma unroll
  for (int q = 0; q < 16; ++q) { s += v[q]; s2 += v[q] * v[q]; }
  #pragma unroll
  for (int o = 1; o < 16; o <<= 1) { s += __shfl_xor(s, o); s2 += __shfl_xor(s2, o); }
  float mean = s * (1.f / HD);
  float var = s2 * (1.f / HD) - mean * mean;
  float rstd = rsqrtf(var + LN_EPS);
  const float* crow = c_all + ((size_t)l * B + bb) * HD + seg * 16;
  const u16* sp = lnps + l * HD + seg * 16;
  const u16* bp = lnpb + l * HD + seg * 16;
  u16* xd = xs_b + r * SLN + seg * 16;
  #pragma unroll
  for (int q = 0; q < 16; ++q) {
    float hv = (v[q] - mean) * rstd * b2f(sp[q]) + b2f(bp[q]) + crow[q];
    xd[q] = f2b(hv);
  }
  __syncthreads();
  int w = t >> 6, ln = t & 63;
  int lr16 = ln & 15, lk = ln >> 4, c0 = w * 64;
  int orow = row0 + lk * 4, ncol = c0 + lr16;
  const u16* arow = xs_b + lr16 * SLN + lk * 8;
  {
    f32x4 acc[4] = {};
    mfma_accum(arow, WtL + (size_t)(c0 + lr16) * HD + lk * 8, acc);
    float* op = hl + (size_t)orow * HD + ncol;
    #pragma unroll
    for (int f = 0; f < 4; ++f)
      #pragma unroll
      for (int j = 0; j < 4; ++j)
        op[j * HD + f * 16] = acc[f][j];
  }
  {
    f32x4 acc[4] = {};
    mfma_accum(arow, WtR + (size_t)(c0 + lr16) * HD + lk * 8, acc);
    float* op = hr + (size_t)orow * HD + ncol;
    #pragma unroll
    for (int f = 0; f < 4; ++f)
      #pragma unroll
      for (int j = 0; j < 4; ++j)
        op[j * HD + f * 16] = acc[f][j];
  }
}
// fp32-input variant: bf16x3 MFMA, staged once, both matrices
__device__ __forceinline__ void lngemm_mfma3(const float* __restrict__ x, const float* __restrict__ c_all,
    const float* __restrict__ lnps, const float* __restrict__ lnpb,
    const u16* __restrict__ WhiL, const u16* __restrict__ WloL,
    const u16* __restrict__ WhiR, const u16* __restrict__ WloR,
    float* __restrict__ hl, float* __restrict__ hr, int l, int row0, u16* xhi, u16* xlo) {
  int t = threadIdx.x;
  int r = t >> 4, seg = t & 15;
  int grow = row0 + r, bb = grow / NS;
  const float* xrow = x + (size_t)grow * HD + seg * 16;
  float v[16]; float s = 0.f, s2 = 0.f;
  #pragma unroll
  for (int q = 0; q < 4; ++q) {
    float4 f4 = *(const float4*)(xrow + 4 * q);
    v[4 * q] = f4.x; v[4 * q + 1] = f4.y; v[4 * q + 2] = f4.z; v[4 * q + 3] = f4.w;
  }
  #pragma unroll
  for (int q = 0; q < 16; ++q) { s += v[q]; s2 += v[q] * v[q]; }
  #pragma unroll
  for (int o = 1; o < 16; o <<= 1) { s += __shfl_xor(s, o); s2 += __shfl_xor(s2, o); }
  float mean = s * (1.f / HD);
  float var = s2 * (1.f / HD) - mean * mean;
  float rstd = rsqrtf(var + LN_EPS);
  const float* crow = c_all + ((size_t)l * B + bb) * HD + seg * 16;
  const float* sp = lnps + l * HD + seg * 16;
  const float* bp = lnpb + l * HD + seg * 16;
  u16* dh = xhi + r * SLN + seg * 16;
  u16* dl = xlo + r * SLN + seg * 16;
  #pragma unroll
  for (int q = 0; q < 16; ++q) {
    float hv = (v[q] - mean) * rstd * sp[q] + bp[q] + crow[q];
    u16 hi = f2b(hv);
    dh[q] = hi;
    dl[q] = f2b(hv - b2f(hi));
  }
  __syncthreads();
  int w = t >> 6, ln = t & 63;
  int lr16 = ln & 15, lk = ln >> 4, c0 = w * 64;
  int orow = row0 + lk * 4, ncol = c0 + lr16;
  const u16* ah = xhi + lr16 * SLN + lk * 8;
  const u16* al = xlo + lr16 * SLN + lk * 8;
  {
    f32x4 acc[4] = {};
    mfma3_accum(ah, al, WhiL + (size_t)(c0 + lr16) * HD + lk * 8,
                WloL + (size_t)(c0 + lr16) * HD + lk * 8, acc);
    float* op = hl + (size_t)orow * HD + ncol;
    #pragma unroll
    for (int f = 0; f < 4; ++f)
      #pragma unroll
      for (int j = 0; j < 4; ++j)
        op[j * HD + f * 16] = acc[f][j];
  }
  {
    f32x4 acc[4] = {};
    mfma3_accum(ah, al, WhiR + (size_t)(c0 + lr16) * HD + lk * 8,
                WloR + (size_t)(c0 + lr16) * HD + lk * 8, acc);
    float* op = hr + (size_t)orow * HD + ncol;
    #pragma unroll
    for (int f = 0; f < 4; ++f)
      #pragma unroll
      for (int j = 0; j < 4; ++j)
        op[j * HD + f * 16] = acc[f][j];
  }
}
__device__ void lngemm_scalar(const float* x, const float* c_all, const float* lnps, const float* lnpb,
                              const float* Wl, const float* Wr, float* hl, float* hr, int l,
                              float (*xs)[HD]) {
  int row0 = blockIdx.x * GROWS, t = threadIdx.x;
  #pragma unroll
  for (int r = 0; r < GROWS; ++r) xs[r][t] = x[(size_t)(row0 + r) * HD + t];
  __syncthreads();
  int w = t >> 6, ln = t & 63;
  #pragma unroll
  for (int rr = 0; rr < 2; ++rr) {
    int r = w + rr * 4;
    float a0 = xs[r][ln], a1 = xs[r][ln + 64], a2 = xs[r][ln + 128], a3 = xs[r][ln + 192];
    float s = a0 + a1 + a2 + a3;
    float s2 = a0 * a0 + a1 * a1 + a2 * a2 + a3 * a3;
    #pragma unroll
    for (int o = 32; o > 0; o >>= 1) { s += __shfl_xor(s, o); s2 += __shfl_xor(s2, o); }
    float mean = s * (1.f / HD), var = s2 * (1.f / HD) - mean * mean;
    float rstd = rsqrtf(var + LN_EPS);
    int bb = (row0 + r) / NS;
    const float* crow = c_all + ((size_t)l * B + bb) * HD;
    const float* sc = lnps + l * HD; const float* bi = lnpb + l * HD;
    xs[r][ln]       = (a0 - mean) * rstd * sc[ln]       + bi[ln]       + crow[ln];
    xs[r][ln + 64]  = (a1 - mean) * rstd * sc[ln + 64]  + bi[ln + 64]  + crow[ln + 64];
    xs[r][ln + 128] = (a2 - mean) * rstd * sc[ln + 128] + bi[ln + 128] + crow[ln + 128];
    xs[r][ln + 192] = (a3 - mean) * rstd * sc[ln + 192] + bi[ln + 192] + crow[ln + 192];
  }
  __syncthreads();
  const float* Wlp = Wl + (size_t)l * HD * HD;
  const float* Wrp = Wr + (size_t)l * HD * HD;
  float acc[GROWS];
  #pragma unroll
  for (int r = 0; r < GROWS; ++r) acc[r] = 0.f;
  for (int k = 0; k < HD; ++k) {
    float wv = Wlp[k * HD + t];
    #pragma unroll
    for (int r = 0; r < GROWS; ++r) acc[r] += xs[r][k] * wv;
  }
  #pragma unroll
  for (int r = 0; r < GROWS; ++r) hl[(size_t)(row0 + r) * HD + t] = acc[r];
  #pragma unroll
  for (int r = 0; r < GROWS; ++r) acc[r] = 0.f;
  for (int k = 0; k < HD; ++k) {
    float wv = Wrp[k * HD + t];
    #pragma unroll
    for (int r = 0; r < GROWS; ++r) acc[r] += xs[r][k] * wv;
  }
  #pragma unroll
  for (int r = 0; r < GROWS; ++r) hr[(size_t)(row0 + r) * HD + t] = acc[r];
}
__global__ void __launch_bounds__(256) k_lngemm_lr(const float* x, const float* c_all,
    const void* lnps, const void* lnpb, const void* Wl, const void* Wr,
    const u16* Wlt, const u16* Wrt,
    const u16* WlHi, const u16* WlLo, const u16* WrHi, const u16* WrLo,
    float* hl, float* hr, int l, const int* flag, int wsok) {
  if (*flag) {
    __shared__ __align__(16) u16 xs_b[16 * SLN];
    if (blockIdx.x >= B * NS / 16) return;  // fused: 288 blocks of the 576 grid
    lngemm_mfma(x, c_all, (const u16*)lnps, (const u16*)lnpb,
                Wlt + (size_t)l * HD * HD, Wrt + (size_t)l * HD * HD,
                hl, hr, l, blockIdx.x * 16, xs_b);
  } else if (wsok) {
    __shared__ __align__(16) u16 xh[16 * SLN];
    __shared__ __align__(16) u16 xl[16 * SLN];
    if (blockIdx.x >= B * NS / 16) return;
    lngemm_mfma3(x, c_all, (const float*)lnps, (const float*)lnpb,
                 WlHi + (size_t)l * HD * HD, WlLo + (size_t)l * HD * HD,
                 WrHi + (size_t)l * HD * HD, WrLo + (size_t)l * HD * HD,
                 hl, hr, l, blockIdx.x * 16, xh, xl);
  } else {
    __shared__ float xs[GROWS][HD];
    lngemm_scalar(x, c_all, (const float*)lnps, (const float*)lnpb,
                  (const float*)Wl, (const float*)Wr, hl, hr, l, xs);
  }
}

// ---------- GATv2 v6: R8 frame + LDS-throughput fixes in the score loop:
// (a) hs = (L<8)?ha:hb via v_cndmask (was a redundant 3rd b128 LDS read);
// (b) tail row h2 hoisted to 16 float4 regs (loop-invariant; uses VGPRs freed
//     when hr2 was dropped);
// (c) softmax max-butterfly removed (shift-invariance; scores bounded |s|<~15,
//     masked lanes contribute exact 0, self-loop guarantees sum>0).
// Score-loop LDS b128/iter: 80 -> 48; serial swizzle chains/pair: 18 -> 12.
template <typename T>
__device__ void gat_body(const float* __restrict__ hl, const float* __restrict__ hr,
                         const T* __restrict__ adj, const T* __restrict__ Wa,
                         T* __restrict__ hg, int l,
                         float* hl_s, float* hr_s, float* attnT, float* wa04_s) {
  const int bid = blockIdx.x;
  const int b = bid >> 2, hh = bid & 3;
  const int t = threadIdx.x;
  const int w = t >> 6, L = t & 63;

  const float* hlbase = hl + (size_t)(b * NS) * HD + hh * NF;
  const float* hrbase = hr + (size_t)(b * NS) * HD + hh * NF;

  // --- adjacency masks: all loads issued up-front, overlap staging ---
  unsigned mA = 0, mB = 0, mT = 0;
  #pragma unroll
  for (int p = 0; p < 9; ++p) {
    int ia = w + 8 * p, ib = ia + 4;
    if (ldv(adj, ia * NS + L) > 0.f) mA |= 1u << p;
    if (ldv(adj, ib * NS + L) > 0.f) mB |= 1u << p;
  }
  if (L < 16) {
    int isel0 = w + ((L < 8) ? 0 : 4);
    #pragma unroll
    for (int p = 0; p < 9; ++p) {
      if (ldv(adj, (isel0 + 8 * p) * NS + 64 + (L & 7)) > 0.f) mT |= 1u << p;
    }
  }

  // own-j hr row (j = L) -> registers
  const float4* hrg1 = (const float4*)(hrbase + L * HD);
  float4 hr1[16];
  #pragma unroll
  for (int q = 0; q < 16; ++q) hr1[q] = hrg1[q];

  if (t < NF) wa04_s[t] = 0.4f * ldv(Wa, l * HD + hh * NF + t);

  // stage hl and hr (all 72 rows)
  const float4* hlg4 = (const float4*)hlbase;
  const float4* hrg4 = (const float4*)hrbase;
  for (int c = t; c < NS * 16; c += 256) {
    int j = c >> 4, q = c & 15;
    *(float4*)&hl_s[j * SH + 4 * q] = hlg4[j * 64 + q];
    *(float4*)&hr_s[j * SH + 4 * q] = hrg4[j * 64 + q];
  }
  __syncthreads();

  // tail row j2 = 64+(L&7) hoisted into registers (loop-invariant)
  const int j2 = 64 + (L & 7);
  float4 h2r[16];
  #pragma unroll
  for (int q = 0; q < 16; ++q) h2r[q] = *(const float4*)&hr_s[j2 * SH + 4 * q];

  float B1 = 0.f, B2 = 0.f;
  #pragma unroll
  for (int q = 0; q < 16; ++q) {
    float4 w4 = *(const float4*)&wa04_s[4 * q];
    B1 = fmaf(w4.x, hr1[q].x, B1); B1 = fmaf(w4.y, hr1[q].y, B1);
    B1 = fmaf(w4.z, hr1[q].z, B1); B1 = fmaf(w4.w, hr1[q].w, B1);
    B2 = fmaf(w4.x, h2r[q].x, B2); B2 = fmaf(w4.y, h2r[q].y, B2);
    B2 = fmaf(w4.z, h2r[q].z, B2); B2 = fmaf(w4.w, h2r[q].w, B2);
  }
  float B15_1 = 1.5f * B1, B15_2 = 1.5f * B2;
  float wa04L = wa04_s[L];
  const bool selA = (L < 8);

  // score + softmax: 9 pairs per wave (ia = w+8p, ib = ia+4)
  for (int p = 0; p < 9; ++p) {
    int ia = w + 8 * p, ib = ia + 4;
    float ava = wa04L * hl_s[ia * SH + L];
    float avb = wa04L * hl_s[ib * SH + L];
    #pragma unroll
    for (int o = 32; o > 0; o >>= 1) { ava += __shfl_xor(ava, o); avb += __shfl_xor(avb, o); }
    float A15a = 1.5f * ava, A15b = 1.5f * avb;

    float acc1a = 0.f, acc1b = 0.f, acc2 = 0.f;
    #pragma unroll
    for (int q = 0; q < 16; ++q) {
      float4 w4 = *(const float4*)&wa04_s[4 * q];
      float4 ha = *(const float4*)&hl_s[ia * SH + 4 * q];
      float4 hb = *(const float4*)&hl_s[ib * SH + 4 * q];
      float4 h2 = h2r[q];
      float e;
      e = ha.x + hr1[q].x; acc1a = fmaf(w4.x, fabsf(e), acc1a);
      e = ha.y + hr1[q].y; acc1a = fmaf(w4.y, fabsf(e), acc1a);
      e = ha.z + hr1[q].z; acc1a = fmaf(w4.z, fabsf(e), acc1a);
      e = ha.w + hr1[q].w; acc1a = fmaf(w4.w, fabsf(e), acc1a);
      e = hb.x + hr1[q].x; acc1b = fmaf(w4.x, fabsf(e), acc1b);
      e = hb.y + hr1[q].y; acc1b = fmaf(w4.y, fabsf(e), acc1b);
      e = hb.z + hr1[q].z; acc1b = fmaf(w4.z, fabsf(e), acc1b);
      e = hb.w + hr1[q].w; acc1b = fmaf(w4.w, fabsf(e), acc1b);
      e = (selA ? ha.x : hb.x) + h2.x; acc2 = fmaf(w4.x, fabsf(e), acc2);
      e = (selA ? ha.y : hb.y) + h2.y; acc2 = fmaf(w4.y, fabsf(e), acc2);
      e = (selA ? ha.z : hb.z) + h2.z; acc2 = fmaf(w4.z, fabsf(e), acc2);
      e = (selA ? ha.w : hb.w) + h2.w; acc2 = fmaf(w4.w, fabsf(e), acc2);
    }
    float e1a = ((mA >> p) & 1u) ? __expf(A15a + B15_1 + acc1a) : 0.f;
    float e2a = (selA && ((mT >> p) & 1u)) ? __expf(A15a + B15_2 + acc2) : 0.f;
    float e1b = ((mB >> p) & 1u) ? __expf(A15b + B15_1 + acc1b) : 0.f;
    float e2b = (L >= 8 && L < 16 && ((mT >> p) & 1u)) ? __expf(A15b + B15_2 + acc2) : 0.f;
    float sea = e1a + e2a, seb = e1b + e2b;
    #pragma unroll
    for (int o = 32; o > 0; o >>= 1) { sea += __shfl_xor(sea, o); seb += __shfl_xor(seb, o); }
    float inva = 1.f / sea, invb = 1.f / seb;
    attnT[L * SA + ia] = e1a * inva;
    attnT[L * SA + ib] = e1b * invb;
    if (L < 8)            attnT[(64 + L) * SA + ia] = e2a * inva;
    if (L >= 8 && L < 16) attnT[(64 + (L & 7)) * SA + ib] = e2b * invb;
  }
  __syncthreads();

  // aggregation: out[i][f=L] = sum_j attnT[j][i] * hr_s[j][L], 18 groups of 4
  for (int p = 0; p < 5; ++p) {
    int g = w + 4 * p;
    if (g >= 18) break;
    int i0 = 4 * g;
    float a0 = 0.f, a1 = 0.f, a2 = 0.f, a3 = 0.f;
    #pragma unroll 4
    for (int j = 0; j < NS; ++j) {
      float4 at = *(const float4*)&attnT[j * SA + i0];
      float hv = hr_s[j * SH + L];
      a0 = fmaf(at.x, hv, a0); a1 = fmaf(at.y, hv, a1);
      a2 = fmaf(at.z, hv, a2); a3 = fmaf(at.w, hv, a3);
    }
    T* o = hg + (size_t)(b * NS + i0) * HD + hh * NF + L;
    stv(o, 0, a0); stv(o, HD, a1); stv(o, 2 * HD, a2); stv(o, 3 * HD, a3);
  }
}
__global__ void __launch_bounds__(256, 1) k_gat(const float* hl, const float* hr, const void* adj,
    const void* Wa, void* hg, int l, const int* flag) {
  __shared__ float hl_s[NS * SH];
  __shared__ float hr_s[NS * SH];
  __shared__ float attnT[NS * SA];
  __shared__ float wa04_s[NF];
  if (*flag) gat_body<bf16>(hl, hr, (const bf16*)adj, (const bf16*)Wa, (bf16*)hg, l, hl_s, hr_s, attnT, wa04_s);
  else gat_body<float>(hl, hr, (const float*)adj, (const float*)Wa, (float*)hg, l, hl_s, hr_s, attnT, wa04_s);
}

// ---------- op GEMM accumulate: x += hg @ op_W[l] + op_b[l]
__device__ void gemmop_scalar(const float* hg, const float* opW, const float* opb, float* x,
                              int l, float (*xs)[HD]) {
  int row0 = blockIdx.x * GROWS; int t = threadIdx.x;
  #pragma unroll
  for (int r = 0; r < GROWS; ++r) xs[r][t] = hg[(size_t)(row0 + r) * HD + t];
  __syncthreads();
  const float* W = opW + (size_t)l * HD * HD;
  float acc[GROWS];
  #pragma unroll
  for (int r = 0; r < GROWS; ++r) acc[r] = 0.f;
  for (int k = 0; k < HD; ++k) {
    float wv = W[k * HD + t];
    #pragma unroll
    for (int r = 0; r < GROWS; ++r) acc[r] += xs[r][k] * wv;
  }
  float bias = opb[l * HD + t];
  #pragma unroll
  for (int r = 0; r < GROWS; ++r) x[(size_t)(row0 + r) * HD + t] += acc[r] + bias;
}
__device__ void gemmop_mfma(const u16* hg_b, const u16* opWt, const u16* opb,
                            float* x, int l, int row0) {
  int t = threadIdx.x, w = t >> 6, ln = t & 63;
  int lr16 = ln & 15, lk = ln >> 4, c0 = w * 64;
  f32x4 acc[4] = {};
  mfma_accum(hg_b + (size_t)(row0 + lr16) * HD + lk * 8,
             opWt + (size_t)l * HD * HD + (size_t)(c0 + lr16) * HD + lk * 8, acc);
  int orow = row0 + lk * 4, ncol = c0 + lr16;
  float* xp = x + (size_t)orow * HD + ncol;
  #pragma unroll
  for (int f = 0; f < 4; ++f) {
    float bias = b2f(opb[l * HD + ncol + f * 16]);
    #pragma unroll
    for (int j = 0; j < 4; ++j)
      xp[j * HD + f * 16] += acc[f][j] + bias;
  }
}
// fp32 path, NO LDS: A-fragments read directly from global fp32 hg and hi/lo-split
// in registers (identical values + reduction order as the old LDS-staged variant).
__device__ void gemmop_mfma3_direct(const float* __restrict__ hg, const u16* __restrict__ opHi,
                                    const u16* __restrict__ opLo, const float* __restrict__ opb,
                                    float* __restrict__ x, int l, int row0) {
  int t = threadIdx.x, w = t >> 6, ln = t & 63;
  int lr16 = ln & 15, lk = ln >> 4, c0 = w * 64;
  const float* arow = hg + (size_t)(row0 + lr16) * HD + lk * 8;
  const u16* bhi = opHi + (size_t)l * HD * HD + (size_t)(c0 + lr16) * HD + lk * 8;
  const u16* blo = opLo + (size_t)l * HD * HD + (size_t)(c0 + lr16) * HD + lk * 8;
  f32x4 acc[4] = {};
  #pragma unroll
  for (int kk = 0; kk < 8; ++kk) {
    float4 f0 = *(const float4*)(arow + kk * 32);
    float4 f1 = *(const float4*)(arow + kk * 32 + 4);
    float v[8] = {f0.x, f0.y, f0.z, f0.w, f1.x, f1.y, f1.z, f1.w};
    union { u16 u[8]; bf16x8 v8; } ah, al;
    #pragma unroll
    for (int e = 0; e < 8; ++e) {
      u16 h = f2b(v[e]);
      ah.u[e] = h;
      al.u[e] = f2b(v[e] - b2f(h));
    }
    #pragma unroll
    for (int f = 0; f < 4; ++f) {
      bf16x8 bh = *(const bf16x8*)(bhi + (size_t)f * 16 * HD + kk * 32);
      bf16x8 bl = *(const bf16x8*)(blo + (size_t)f * 16 * HD + kk * 32);
      acc[f] = __builtin_amdgcn_mfma_f32_16x16x32_bf16(al.v8, bh, acc[f], 0, 0, 0);
      acc[f] = __builtin_amdgcn_mfma_f32_16x16x32_bf16(ah.v8, bl, acc[f], 0, 0, 0);
      acc[f] = __builtin_amdgcn_mfma_f32_16x16x32_bf16(ah.v8, bh, acc[f], 0, 0, 0);
    }
  }
  int orow = row0 + lk * 4, ncol = c0 + lr16;
  float* xp = x + (size_t)orow * HD + ncol;
  #pragma unroll
  for (int f = 0; f < 4; ++f) {
    float bias = opb[l * HD + ncol + f * 16];
    #pragma unroll
    for (int j = 0; j < 4; ++j)
      xp[j * HD + f * 16] += acc[f][j] + bias;
  }
}
__global__ void __launch_bounds__(256) k_gemm_op(const void* hg, const void* opW, const u16* opWt,
    const u16* opHi, const u16* opLo, const void* opb, float* x, int l,
    const int* flag, int wsok) {
  if (*flag) {
    if (blockIdx.x < (B * NS / 16))
      gemmop_mfma((const u16*)hg, opWt, (const u16*)opb, x, l, blockIdx.x * 16);
  } else if (wsok) {
    if (blockIdx.x < (B * NS / 16))
      gemmop_mfma3_direct((const float*)hg, opHi, opLo, (const float*)opb, x, l, blockIdx.x * 16);
  } else {
    __shared__ float xs[GROWS][HD];
    gemmop_scalar((const float*)hg, (const float*)opW, (const float*)opb, x, l, xs);
  }
}

// ---------- heads: 1024 threads/block, 4-way split on both the mean (s-axis) and GEMM (k-axis)
#define HTOT (NC + 3 + NS + NS + 128)   // 385
#define HPAD 392

template <typename T>
__device__ void heads_body(const float* x,
    const T* cardW, const T* cardb, const T* atW, const T* atb,
    const T* srcW, const T* srcb, const T* tgtW, const T* tgtb,
    const T* v1W, const T* v1b, const T* v2W, const T* v2b,
    T* out, float* spart, float* sge, float* hpart, float* sh1) {
  int b = blockIdx.x, t = threadIdx.x;
  int sq = t >> 8, tt = t & 255;
  float acc = 0.f;
  for (int ss = sq; ss < NS; ss += 4) acc += x[(size_t)(b * NS + ss) * HD + tt];
  spart[sq * HD + tt] = acc;
  __syncthreads();
  if (t < HD) sge[t] = (spart[t] + spart[HD + t] + spart[2 * HD + t] + spart[3 * HD + t]) * (1.f / NS);
  __syncthreads();
  #pragma unroll
  for (int pass = 0; pass < 2; ++pass) {
    int col = tt + pass * 256;
    if (col < HTOT) {
      const T* Wp; int stride, off;
      if (col < NC) { Wp = cardW; stride = NC; off = col; }
      else if (col < NC + 3) { Wp = atW; stride = 3; off = col - NC; }
      else if (col < NC + 3 + NS) { Wp = srcW; stride = NS; off = col - (NC + 3); }
      else if (col < NC + 3 + 2 * NS) { Wp = tgtW; stride = NS; off = col - (NC + 3 + NS); }
      else { Wp = v1W; stride = 128; off = col - (NC + 3 + 2 * NS); }
      const float* gp = sge + sq * 64;
      float p = 0.f;
      #pragma unroll 8
      for (int k = 0; k < 64; ++k) p += gp[k] * ldv(Wp, (sq * 64 + k) * stride + off);
      hpart[sq * HPAD + col] = p;
    }
  }
  __syncthreads();
  if (t < HTOT) {
    float v = hpart[t] + hpart[HPAD + t] + hpart[2 * HPAD + t] + hpart[3 * HPAD + t];
    if (t < NC) stv(out, b * NC + t, v + ldv(cardb, t));
    else if (t < NC + 3) stv(out, B * NC + b * 3 + (t - NC), v + ldv(atb, t - NC));
    else if (t < NC + 3 + NS) stv(out, B * NC + B * 3 + b * NS + (t - NC - 3), v + ldv(srcb, t - NC - 3));
    else if (t < NC + 3 + 2 * NS) stv(out, B * NC + B * 3 + B * NS + b * NS + (t - NC - 3 - NS), v + ldv(tgtb, t - NC - 3 - NS));
    else { int o = t - (NC + 3 + 2 * NS); sh1[o] = fmaxf(v + ldv(v1b, o), 0.f); }
  }
  __syncthreads();
  if (t < 64) {
    float pv = sh1[t] * ldv(v2W, t) + sh1[t + 64] * ldv(v2W, t + 64);
    #pragma unroll
    for (int o = 32; o > 0; o >>= 1) pv += __shfl_xor(pv, o);
    if (t == 0) stv(out, B * (NC + 3 + NS + NS) + b, tanhf(pv + ldv(v2b, 0)));
  }
}
__global__ void __launch_bounds__(1024) k_heads(const float* x,
    const void* cardW, const void* cardb, const void* atW, const void* atb,
    const void* srcW, const void* srcb, const void* tgtW, const void* tgtb,
    const void* v1W, const void* v1b, const void* v2W, const void* v2b,
    void* out, const int* flag) {
  __shared__ float spart[4 * HD];
  __shared__ float sge[HD];
  __shared__ float hpart[4 * HPAD];
  __shared__ float sh1[128];
  if (*flag) heads_body<bf16>(x, (const bf16*)cardW, (const bf16*)cardb, (const bf16*)atW,
                              (const bf16*)atb, (const bf16*)srcW, (const bf16*)srcb,
                              (const bf16*)tgtW, (const bf16*)tgtb, (const bf16*)v1W,
                              (const bf16*)v1b, (const bf16*)v2W, (const bf16*)v2b,
                              (bf16*)out, spart, sge, hpart, sh1);
  else heads_body<float>(x, (const float*)cardW, (const float*)cardb, (const float*)atW,
                         (const float*)atb, (const float*)srcW, (const float*)srcb,
                         (const float*)tgtW, (const float*)tgtb, (const float*)v1W,
                         (const float*)v1b, (const float*)v2W, (const float*)v2b,
                         (float*)out, spart, sge, hpart, sh1);
}

extern "C" void kernel_launch(void* const* d_in, const int* in_sizes, int n_in,
                              void* d_out, int out_size, void* d_ws, size_t ws_size,
                              hipStream_t stream) {
  const void* spatial = d_in[0];
  const void* cardctx = d_in[1];
  const void* adj = d_in[2];
  const void* ctxW = d_in[3]; const void* ctxb = d_in[4];
  const void* lncs = d_in[5]; const void* lncb = d_in[6];
  const void* inW = d_in[7];  const void* inb = d_in[8];
  const void* lnps = d_in[9]; const void* lnpb = d_in[10];
  const void* cpW = d_in[11]; const void* cpb = d_in[12];
  const void* Wl = d_in[13];  const void* Wr = d_in[14]; const void* Wa = d_in[15];
  const void* opW = d_in[16]; const void* opb = d_in[17];
  const void* cardW = d_in[18]; const void* cardb = d_in[19];
  const void* atW = d_in[20];   const void* atb = d_in[21];
  const void* srcW = d_in[22];  const void* srcb = d_in[23];
  const void* tgtW = d_in[24];  const void* tgtb = d_in[25];
  const void* v1W = d_in[26];   const void* v1b = d_in[27];
  const void* v2W = d_in[28];   const void* v2b = d_in[29];

  int* flag = (int*)d_ws;
  float* fb = (float*)((char*)d_ws + 256);
  float* g     = fb;                               // B*HD
  float* c_all = g + B * HD;                       // NL*B*HD
  float* x     = c_all + NL * B * HD;              // B*NS*HD
  float* hgf   = x + (size_t)B * NS * HD;          // B*NS*HD
  float* hl    = hgf + (size_t)B * NS * HD;        // B*NS*HD
  float* hr    = hl + (size_t)B * NS * HD;         // B*NS*HD

  // Base footprint (Round-2-proven): 256 + 4,800,512 floats = 18.32 MB.
  size_t base_bytes = 256 + ((size_t)B * HD + (size_t)NL * B * HD + 4 * (size_t)B * NS * HD) * 4;
  // Pool: max(bf16-mode: g_b + 4 transposed bf16 weights = 2.13 MB,
  //           fp32-mode: 6 hi/lo transposed bf16 weights  = 3.00 MB)
  size_t pool_b16 = ((size_t)B * HD + 4 * (size_t)NL * HD * HD) * 2;
  size_t pool_f32 = (size_t)6 * NL * HD * HD * 2;
  size_t pool_bytes = pool_f32 > pool_b16 ? pool_f32 : pool_b16;
  int wsok = (ws_size >= base_bytes + pool_bytes) ? 1 : 0;

  // If ws is generous: pool appended past base. Otherwise: fall back to the exact
  // Round-2 layout (pool aliased in hgf's upper half; fp32 path runs scalar).
  u16* pool = wsok ? (u16*)((char*)d_ws + base_bytes)
                   : (u16*)(hgf + (size_t)B * NS * HD / 2);
  // bf16-input mode pointers
  u16* g_b  = pool;
  u16* Wlt  = g_b + B * HD;
  u16* Wrt  = Wlt + NL * HD * HD;
  u16* opWt = Wrt + NL * HD * HD;
  u16* cpWt = opWt + NL * HD * HD;
  // fp32-input mode pointers (alias the same pool; modes are mutually exclusive)
  u16* WlHi = pool;              u16* WlLo = WlHi + NL * HD * HD;
  u16* WrHi = WlLo + NL * HD * HD; u16* WrLo = WrHi + NL * HD * HD;
  u16* opHi = WrLo + NL * HD * HD; u16* opLo = opHi + NL * HD * HD;

  k_detect<<<1, 64, 0, stream>>>(adj, flag);
  k_prep<<<256, 256, 0, stream>>>(Wl, Wr, opW, cpW, Wlt, Wrt, opWt, cpWt, flag);
  if (wsok)
    k_prep32<<<192, 256, 0, stream>>>(Wl, Wr, opW, WlHi, WlLo, WrHi, WrLo, opHi, opLo, flag);
  k_ctx<<<B, HD, 0, stream>>>(cardctx, ctxW, ctxb, lncs, lncb, g, g_b, flag);
  k_inproj<<<B * NS, HD, 0, stream>>>(spatial, inW, inb, x, flag);
  k_cproj_all<<<B * NL, HD, 0, stream>>>(g, g_b, cpW, cpWt, cpb, c_all, flag);
  for (int l = 0; l < NL; ++l) {
    k_lngemm_lr<<<B * NS / GROWS, 256, 0, stream>>>(x, c_all, lnps, lnpb, Wl, Wr, Wlt, Wrt,
                                                    WlHi, WlLo, WrHi, WrLo, hl, hr, l, flag, wsok);
    k_gat<<<B * NH, 256, 0, stream>>>(hl, hr, adj, Wa, hgf, l, flag);
    k_gemm_op<<<B * NS / GROWS, 256, 0, stream>>>(hgf, opW, opWt, opHi, opLo, opb, x, l, flag, wsok);
  }
  k_heads<<<B, 1024, 0, stream>>>(x, cardW, cardb, atW, atb, srcW, srcb, tgtW, tgtb,
                                  v1W, v1b, v2W, v2b, d_out, flag);
}

// Round 10
// 473.296 us; speedup vs baseline: 1.0444x; 1.0444x over previous
//
#include <hip/hip_runtime.h>
#include <hip/hip_bf16.h>
#include <math.h>

#define B 64
#define NP 32
#define NS 72
#define NH 4
#define NF 64
#define HD 256
#define CTXD 112
#define NL 4
#define NC 110
#define LN_EPS 1e-6f
#define GROWS 8

// LDS strides for gat
#define SH 68   // hl_s / hr_s row stride (floats)
#define SA 76   // attnT row stride
#define SLN 264 // bf16 LDS row stride for MFMA A tiles (528B: 2-way banks on b128)

typedef __hip_bfloat16 bf16;
typedef unsigned short u16;
typedef float f32x4 __attribute__((ext_vector_type(4)));
typedef __bf16 bf16x8 __attribute__((ext_vector_type(8)));

__device__ __forceinline__ float ldv(const float* p, int i) { return p[i]; }
__device__ __forceinline__ float ldv(const bf16* p, int i) { return __bfloat162float(p[i]); }
__device__ __forceinline__ void stv(float* p, int i, float v) { p[i] = v; }
__device__ __forceinline__ void stv(bf16* p, int i, float v) { p[i] = __float2bfloat16(v); }
__device__ __forceinline__ u16 f2b(float f) {
  union { bf16 h; u16 u; } cv; cv.h = __float2bfloat16(f); return cv.u;
}
__device__ __forceinline__ float b2f(u16 u) { return __uint_as_float((unsigned)u << 16); }

// ---------- dtype detector: adj[0,0]==1.0 guaranteed (self-loop).
__global__ void k_detect(const void* adj, int* flag) {
  if (threadIdx.x == 0 && blockIdx.x == 0) {
    *flag = (((const u16*)adj)[0] == 0x3F80u) ? 1 : 0;
  }
}

// ---------- one-time weight transpose (bf16-input mode): W[l][k][n] -> Wt[l][n][k]
__global__ void __launch_bounds__(256) k_prep(const void* Wl, const void* Wr, const void* opW,
    const void* cpW, u16* Wlt, u16* Wrt, u16* opWt, u16* cpWt, const int* flag) {
  if (!*flag) return;
  __shared__ __align__(16) u16 tile[64][72];
  int bid = blockIdx.x, t = threadIdx.x;
  int tensor = bid >> 6, layer = (bid >> 4) & 3, ti = (bid >> 2) & 3, tj = bid & 3;
  const u16* srcs[4] = {(const u16*)Wl, (const u16*)Wr, (const u16*)opW, (const u16*)cpW};
  u16* dsts[4] = {Wlt, Wrt, opWt, cpWt};
  const u16* src = srcs[tensor] + (size_t)layer * HD * HD + (ti * 64) * HD + tj * 64;
  u16* dst = dsts[tensor] + (size_t)layer * HD * HD + (tj * 64) * HD + ti * 64;
  int r = t >> 2, cq = (t & 3) * 16;
  *(uint4*)&tile[r][cq]     = *(const uint4*)(src + r * HD + cq);
  *(uint4*)&tile[r][cq + 8] = *(const uint4*)(src + r * HD + cq + 8);
  __syncthreads();
  unsigned u[8];
  #pragma unroll
  for (int i = 0; i < 8; ++i)
    u[i] = (unsigned)tile[cq + 2 * i][r] | ((unsigned)tile[cq + 2 * i + 1][r] << 16);
  *(uint4*)(dst + r * HD + cq) = make_uint4(u[0], u[1], u[2], u[3]);
  *(uint4*)(dst + r * HD + cq + 8) = make_uint4(u[4], u[5], u[6], u[7]);
}

// ---------- one-time fp32 weight transpose+split (fp32-input mode, ws-permitting):
// W[l][k][n] fp32 -> Whi[l][n][k], Wlo[l][n][k] bf16 (Ootomo hi/lo split).
__global__ void __launch_bounds__(256) k_prep32(const void* Wl, const void* Wr, const void* opW,
    u16* WlHi, u16* WlLo, u16* WrHi, u16* WrLo, u16* opHi, u16* opLo, const int* flag) {
  if (*flag) return;  // fp32 mode only
  __shared__ float tile[64][65];
  int bid = blockIdx.x, t = threadIdx.x;
  int tensor = bid >> 6, layer = (bid >> 4) & 3, ti = (bid >> 2) & 3, tj = bid & 3;
  const float* srcs[3] = {(const float*)Wl, (const float*)Wr, (const float*)opW};
  const float* src = srcs[tensor] + (size_t)layer * HD * HD + (ti * 64) * HD + tj * 64;
  int r = t >> 2, cq = (t & 3) * 16;
  #pragma unroll
  for (int q = 0; q < 4; ++q) {
    float4 f4 = *(const float4*)(src + r * HD + cq + 4 * q);
    tile[r][cq + 4 * q]     = f4.x; tile[r][cq + 4 * q + 1] = f4.y;
    tile[r][cq + 4 * q + 2] = f4.z; tile[r][cq + 4 * q + 3] = f4.w;
  }
  __syncthreads();
  u16* Hs[3] = {WlHi, WrHi, opHi};
  u16* Ls[3] = {WlLo, WrLo, opLo};
  u16* dstH = Hs[tensor] + (size_t)layer * HD * HD + (tj * 64) * HD + ti * 64;
  u16* dstL = Ls[tensor] + (size_t)layer * HD * HD + (tj * 64) * HD + ti * 64;
  u16 hb[16], lb[16];
  #pragma unroll
  for (int i = 0; i < 16; ++i) {
    float wv = tile[cq + i][r];
    u16 hi = f2b(wv);
    hb[i] = hi;
    lb[i] = f2b(wv - b2f(hi));
  }
  unsigned uh[8], ul[8];
  #pragma unroll
  for (int i = 0; i < 8; ++i) {
    uh[i] = (unsigned)hb[2 * i] | ((unsigned)hb[2 * i + 1] << 16);
    ul[i] = (unsigned)lb[2 * i] | ((unsigned)lb[2 * i + 1] << 16);
  }
  *(uint4*)(dstH + r * HD + cq)     = make_uint4(uh[0], uh[1], uh[2], uh[3]);
  *(uint4*)(dstH + r * HD + cq + 8) = make_uint4(uh[4], uh[5], uh[6], uh[7]);
  *(uint4*)(dstL + r * HD + cq)     = make_uint4(ul[0], ul[1], ul[2], ul[3]);
  *(uint4*)(dstL + r * HD + cq + 8) = make_uint4(ul[4], ul[5], ul[6], ul[7]);
}

__device__ __forceinline__ void block_reduce_2(float& a, float& b, float* sred, int t) {
  #pragma unroll
  for (int o = 32; o > 0; o >>= 1) { a += __shfl_down(a, o); b += __shfl_down(b, o); }
  if ((t & 63) == 0) { sred[(t >> 6) * 2] = a; sred[(t >> 6) * 2 + 1] = b; }
  __syncthreads();
  a = sred[0] + sred[2] + sred[4] + sred[6];
  b = sred[1] + sred[3] + sred[5] + sred[7];
}

// ---------- shared MFMA cores: one 16(row)x64(col) C-quadrant per wave over K=256.
// A and B fragments use the SAME k-slot order -> contraction correct for any HW k-map.
__device__ __forceinline__ void mfma_accum(const u16* __restrict__ arow,
                                           const u16* __restrict__ brow, f32x4* acc) {
  #pragma unroll
  for (int kk = 0; kk < 8; ++kk) {
    bf16x8 a = *(const bf16x8*)(arow + kk * 32);
    #pragma unroll
    for (int f = 0; f < 4; ++f) {
      bf16x8 bv = *(const bf16x8*)(brow + (size_t)f * 16 * HD + kk * 32);
      acc[f] = __builtin_amdgcn_mfma_f32_16x16x32_bf16(a, bv, acc[f], 0, 0, 0);
    }
  }
}
// bf16x3 (Ootomo): acc += Ahi*Bhi + Ahi*Blo + Alo*Bhi  (Alo*Blo ~ 2^-18, dropped)
__device__ __forceinline__ void mfma3_accum(const u16* __restrict__ ahi, const u16* __restrict__ alo,
                                            const u16* __restrict__ bhi, const u16* __restrict__ blo,
                                            f32x4* acc) {
  #pragma unroll
  for (int kk = 0; kk < 8; ++kk) {
    bf16x8 ah = *(const bf16x8*)(ahi + kk * 32);
    bf16x8 al = *(const bf16x8*)(alo + kk * 32);
    #pragma unroll
    for (int f = 0; f < 4; ++f) {
      bf16x8 bh = *(const bf16x8*)(bhi + (size_t)f * 16 * HD + kk * 32);
      bf16x8 bl = *(const bf16x8*)(blo + (size_t)f * 16 * HD + kk * 32);
      acc[f] = __builtin_amdgcn_mfma_f32_16x16x32_bf16(al, bh, acc[f], 0, 0, 0);
      acc[f] = __builtin_amdgcn_mfma_f32_16x16x32_bf16(ah, bl, acc[f], 0, 0, 0);
      acc[f] = __builtin_amdgcn_mfma_f32_16x16x32_bf16(ah, bh, acc[f], 0, 0, 0);
    }
  }
}

// ---------- context head: g = relu(LN(ctx @ ctx_W + ctx_b)); also bf16 copy for bf16-MFMA path
template <typename T>
__device__ void ctx_body(const T* cardctx, const T* ctxW, const T* ctxb,
                         const T* lncs, const T* lncb, float* g, u16* gb,
                         float* sred, float* sctx) {
  int b = blockIdx.x, t = threadIdx.x;
  if (t < CTXD) sctx[t] = ldv(cardctx, b * CTXD + t);
  __syncthreads();
  float acc = ldv(ctxb, t);
  for (int k = 0; k < CTXD; ++k) acc += sctx[k] * ldv(ctxW, k * HD + t);
  float a = acc, bb = acc * acc;
  block_reduce_2(a, bb, sred, t);
  float mean = a * (1.f / HD);
  float var = bb * (1.f / HD) - mean * mean;
  float r = rsqrtf(var + LN_EPS);
  float v = (acc - mean) * r * ldv(lncs, t) + ldv(lncb, t);
  float rv = fmaxf(v, 0.f);
  g[b * HD + t] = rv;
  if (gb) gb[b * HD + t] = f2b(rv);
}
__global__ void __launch_bounds__(256) k_ctx(const void* cardctx, const void* ctxW, const void* ctxb,
    const void* lncs, const void* lncb, float* g, u16* gb, const int* flag) {
  __shared__ float sred[8];
  __shared__ float sctx[CTXD];
  if (*flag) ctx_body<bf16>((const bf16*)cardctx, (const bf16*)ctxW, (const bf16*)ctxb,
                            (const bf16*)lncs, (const bf16*)lncb, g, gb, sred, sctx);
  else ctx_body<float>((const float*)cardctx, (const float*)ctxW, (const float*)ctxb,
                       (const float*)lncs, (const float*)lncb, g, (u16*)0, sred, sctx);
}

// ---------- input projection
template <typename T>
__device__ void inproj_body(const T* spat, const T* inW, const T* inb, float* x, float* ssp) {
  int blk = blockIdx.x; int b = blk / NS; int s = blk % NS; int t = threadIdx.x;
  if (t < NP) ssp[t] = ldv(spat, (b * NP + t) * NS + s);
  __syncthreads();
  float acc = ldv(inb, t);
  #pragma unroll 8
  for (int p = 0; p < NP; ++p) acc += ssp[p] * ldv(inW, p * HD + t);
  x[blk * HD + t] = acc;
}
__global__ void __launch_bounds__(256) k_inproj(const void* spat, const void* inW, const void* inb,
                         float* x, const int* flag) {
  __shared__ float ssp[NP];
  if (*flag) inproj_body<bf16>((const bf16*)spat, (const bf16*)inW, (const bf16*)inb, x, ssp);
  else inproj_body<float>((const float*)spat, (const float*)inW, (const float*)inb, x, ssp);
}

// ---------- context projections, all 4 layers at once (layer-invariant -> hoisted)
__device__ void cproj_scalar(const float* g, const float* cpW, const float* cpb,
                             float* c_all, int l, int b, float* sg) {
  int t = threadIdx.x;
  sg[t] = g[b * HD + t];
  __syncthreads();
  const float* W = cpW + (size_t)l * HD * HD;
  float acc = cpb[l * HD + t];
  for (int k = 0; k < HD; ++k) acc += sg[k] * W[k * HD + t];
  c_all[((size_t)l * B + b) * HD + t] = acc;
}
__device__ void cproj_mfma(const u16* g_b, const u16* cpWt, const u16* cpb,
                           float* c_all, int l, int row0) {
  int t = threadIdx.x, w = t >> 6, ln = t & 63;
  int lr16 = ln & 15, lk = ln >> 4, c0 = w * 64;
  f32x4 acc[4] = {};
  const u16* arow = g_b + (size_t)(row0 + lr16) * HD + lk * 8;
  const u16* brow = cpWt + (size_t)l * HD * HD + (size_t)(c0 + lr16) * HD + lk * 8;
  mfma_accum(arow, brow, acc);
  int orow = row0 + lk * 4, ncol = c0 + lr16;
  #pragma unroll
  for (int f = 0; f < 4; ++f) {
    float bias = b2f(cpb[l * HD + ncol + f * 16]);
    #pragma unroll
    for (int j = 0; j < 4; ++j)
      c_all[((size_t)l * B + orow + j) * HD + ncol + f * 16] = acc[f][j] + bias;
  }
}
__global__ void __launch_bounds__(256) k_cproj_all(const float* g, const u16* g_b,
    const void* cpW, const u16* cpWt, const void* cpb, float* c_all, const int* flag) {
  __shared__ float sg[HD];
  if (*flag) {
    if (blockIdx.x < 16)
      cproj_mfma(g_b, cpWt, (const u16*)cpb, c_all, blockIdx.x >> 2, (blockIdx.x & 3) * 16);
  } else {
    cproj_scalar(g, (const float*)cpW, (const float*)cpb, c_all, blockIdx.x >> 6, blockIdx.x & 63, sg);
  }
}

// ---------- fused LN + dual GEMM: hl = (LN(x)+c) @ Wl, hr = (LN(x)+c) @ Wr
// R8-proven mat-split form: 576 blocks, each does ONE matrix (2x TLP beats staged-once;
// the R9 fusion halved block count and serialized two MFMA passes -> regression).
__device__ __forceinline__ void lngemm_mfma(const float* __restrict__ x, const float* __restrict__ c_all,
    const u16* __restrict__ lnps, const u16* __restrict__ lnpb,
    const u16* __restrict__ Wt, float* __restrict__ outm, int l, int row0, u16* xs_b) {
  int t = threadIdx.x;
  int r = t >> 4, seg = t & 15;
  int grow = row0 + r, bb = grow / NS;
  const float* xrow = x + (size_t)grow * HD + seg * 16;
  float v[16]; float s = 0.f, s2 = 0.f;
  #pragma unroll
  for (int q = 0; q < 4; ++q) {
    float4 f4 = *(const float4*)(xrow + 4 * q);
    v[4 * q] = f4.x; v[4 * q + 1] = f4.y; v[4 * q + 2] = f4.z; v[4 * q + 3] = f4.w;
  }
  #pragma unroll
  for (int q = 0; q < 16; ++q) { s += v[q]; s2 += v[q] * v[q]; }
  #pragma unroll
  for (int o = 1; o < 16; o <<= 1) { s += __shfl_xor(s, o); s2 += __shfl_xor(s2, o); }
  float mean = s * (1.f / HD);
  float var = s2 * (1.f / HD) - mean * mean;
  float rstd = rsqrtf(var + LN_EPS);
  const float* crow = c_all + ((size_t)l * B + bb) * HD + seg * 16;
  const u16* sp = lnps + l * HD + seg * 16;
  const u16* bp = lnpb + l * HD + seg * 16;
  u16* xd = xs_b + r * SLN + seg * 16;
  #pragma unroll
  for (int q = 0; q < 16; ++q) {
    float hv = (v[q] - mean) * rstd * b2f(sp[q]) + b2f(bp[q]) + crow[q];
    xd[q] = f2b(hv);
  }
  __syncthreads();
  int w = t >> 6, ln = t & 63;
  int lr16 = ln & 15, lk = ln >> 4, c0 = w * 64;
  f32x4 acc[4] = {};
  mfma_accum(xs_b + lr16 * SLN + lk * 8, Wt + (size_t)(c0 + lr16) * HD + lk * 8, acc);
  int orow = row0 + lk * 4, ncol = c0 + lr16;
  float* op = outm + (size_t)orow * HD + ncol;
  #pragma unroll
  for (int f = 0; f < 4; ++f)
    #pragma unroll
    for (int j = 0; j < 4; ++j)
      op[j * HD + f * 16] = acc[f][j];
}
// fp32-input variant: bf16x3 MFMA (hi/lo split A in LDS, hi/lo split W from k_prep32)
__device__ __forceinline__ void lngemm_mfma3(const float* __restrict__ x, const float* __restrict__ c_all,
    const float* __restrict__ lnps, const float* __restrict__ lnpb,
    const u16* __restrict__ Whi, const u16* __restrict__ Wlo,
    float* __restrict__ outm, int l, int row0, u16* xhi, u16* xlo) {
  int t = threadIdx.x;
  int r = t >> 4, seg = t & 15;
  int grow = row0 + r, bb = grow / NS;
  const float* xrow = x + (size_t)grow * HD + seg * 16;
  float v[16]; float s = 0.f, s2 = 0.f;
  #pragma unroll
  for (int q = 0; q < 4; ++q) {
    float4 f4 = *(const float4*)(xrow + 4 * q);
    v[4 * q] = f4.x; v[4 * q + 1] = f4.y; v[4 * q + 2] = f4.z; v[4 * q + 3] = f4.w;
  }
  #pragma unroll
  for (int q = 0; q < 16; ++q) { s += v[q]; s2 += v[q] * v[q]; }
  #pragma unroll
  for (int o = 1; o < 16; o <<= 1) { s += __shfl_xor(s, o); s2 += __shfl_xor(s2, o); }
  float mean = s * (1.f / HD);
  float var = s2 * (1.f / HD) - mean * mean;
  float rstd = rsqrtf(var + LN_EPS);
  const float* crow = c_all + ((size_t)l * B + bb) * HD + seg * 16;
  const float* sp = lnps + l * HD + seg * 16;
  const float* bp = lnpb + l * HD + seg * 16;
  u16* dh = xhi + r * SLN + seg * 16;
  u16* dl = xlo + r * SLN + seg * 16;
  #pragma unroll
  for (int q = 0; q < 16; ++q) {
    float hv = (v[q] - mean) * rstd * sp[q] + bp[q] + crow[q];
    u16 hi = f2b(hv);
    dh[q] = hi;
    dl[q] = f2b(hv - b2f(hi));
  }
  __syncthreads();
  int w = t >> 6, ln = t & 63;
  int lr16 = ln & 15, lk = ln >> 4, c0 = w * 64;
  f32x4 acc[4] = {};
  mfma3_accum(xhi + lr16 * SLN + lk * 8, xlo + lr16 * SLN + lk * 8,
              Whi + (size_t)(c0 + lr16) * HD + lk * 8,
              Wlo + (size_t)(c0 + lr16) * HD + lk * 8, acc);
  int orow = row0 + lk * 4, ncol = c0 + lr16;
  float* op = outm + (size_t)orow * HD + ncol;
  #pragma unroll
  for (int f = 0; f < 4; ++f)
    #pragma unroll
    for (int j = 0; j < 4; ++j)
      op[j * HD + f * 16] = acc[f][j];
}
__device__ void lngemm_scalar(const float* x, const float* c_all, const float* lnps, const float* lnpb,
                              const float* Wl, const float* Wr, float* hl, float* hr, int l,
                              float (*xs)[HD]) {
  int row0 = blockIdx.x * GROWS, t = threadIdx.x;
  #pragma unroll
  for (int r = 0; r < GROWS; ++r) xs[r][t] = x[(size_t)(row0 + r) * HD + t];
  __syncthreads();
  int w = t >> 6, ln = t & 63;
  #pragma unroll
  for (int rr = 0; rr < 2; ++rr) {
    int r = w + rr * 4;
    float a0 = xs[r][ln], a1 = xs[r][ln + 64], a2 = xs[r][ln + 128], a3 = xs[r][ln + 192];
    float s = a0 + a1 + a2 + a3;
    float s2 = a0 * a0 + a1 * a1 + a2 * a2 + a3 * a3;
    #pragma unroll
    for (int o = 32; o > 0; o >>= 1) { s += __shfl_xor(s, o); s2 += __shfl_xor(s2, o); }
    float mean = s * (1.f / HD), var = s2 * (1.f / HD) - mean * mean;
    float rstd = rsqrtf(var + LN_EPS);
    int bb = (row0 + r) / NS;
    const float* crow = c_all + ((size_t)l * B + bb) * HD;
    const float* sc = lnps + l * HD; const float* bi = lnpb + l * HD;
    xs[r][ln]       = (a0 - mean) * rstd * sc[ln]       + bi[ln]       + crow[ln];
    xs[r][ln + 64]  = (a1 - mean) * rstd * sc[ln + 64]  + bi[ln + 64]  + crow[ln + 64];
    xs[r][ln + 128] = (a2 - mean) * rstd * sc[ln + 128] + bi[ln + 128] + crow[ln + 128];
    xs[r][ln + 192] = (a3 - mean) * rstd * sc[ln + 192] + bi[ln + 192] + crow[ln + 192];
  }
  __syncthreads();
  const float* Wlp = Wl + (size_t)l * HD * HD;
  const float* Wrp = Wr + (size_t)l * HD * HD;
  float acc[GROWS];
  #pragma unroll
  for (int r = 0; r < GROWS; ++r) acc[r] = 0.f;
  for (int k = 0; k < HD; ++k) {
    float wv = Wlp[k * HD + t];
    #pragma unroll
    for (int r = 0; r < GROWS; ++r) acc[r] += xs[r][k] * wv;
  }
  #pragma unroll
  for (int r = 0; r < GROWS; ++r) hl[(size_t)(row0 + r) * HD + t] = acc[r];
  #pragma unroll
  for (int r = 0; r < GROWS; ++r) acc[r] = 0.f;
  for (int k = 0; k < HD; ++k) {
    float wv = Wrp[k * HD + t];
    #pragma unroll
    for (int r = 0; r < GROWS; ++r) acc[r] += xs[r][k] * wv;
  }
  #pragma unroll
  for (int r = 0; r < GROWS; ++r) hr[(size_t)(row0 + r) * HD + t] = acc[r];
}
__global__ void __launch_bounds__(256) k_lngemm_lr(const float* x, const float* c_all,
    const void* lnps, const void* lnpb, const void* Wl, const void* Wr,
    const u16* Wlt, const u16* Wrt,
    const u16* WlHi, const u16* WlLo, const u16* WrHi, const u16* WrLo,
    float* hl, float* hr, int l, const int* flag, int wsok) {
  if (*flag) {
    __shared__ __align__(16) u16 xs_b[16 * SLN];
    int mat = blockIdx.x & 1, rt = blockIdx.x >> 1;
    lngemm_mfma(x, c_all, (const u16*)lnps, (const u16*)lnpb,
                (mat ? Wrt : Wlt) + (size_t)l * HD * HD, mat ? hr : hl, l, rt * 16, xs_b);
  } else if (wsok) {
    __shared__ __align__(16) u16 xh[16 * SLN];
    __shared__ __align__(16) u16 xl[16 * SLN];
    int mat = blockIdx.x & 1, rt = blockIdx.x >> 1;
    lngemm_mfma3(x, c_all, (const float*)lnps, (const float*)lnpb,
                 (mat ? WrHi : WlHi) + (size_t)l * HD * HD,
                 (mat ? WrLo : WlLo) + (size_t)l * HD * HD,
                 mat ? hr : hl, l, rt * 16, xh, xl);
  } else {
    __shared__ float xs[GROWS][HD];
    lngemm_scalar(x, c_all, (const float*)lnps, (const float*)lnpb,
                  (const float*)Wl, (const float*)Wr, hl, hr, l, xs);
  }
}

// ---------- GATv2 v6 (kept from R9): R8 frame + LDS-throughput fixes:
// (a) hs = (L<8)?ha:hb via v_cndmask; (b) tail row h2 hoisted to regs;
// (c) softmax max-butterfly removed (shift-invariance, bounded scores,
//     masked lanes contribute exact 0, self-loop guarantees sum>0).
template <typename T>
__device__ void gat_body(const float* __restrict__ hl, const float* __restrict__ hr,
                         const T* __restrict__ adj, const T* __restrict__ Wa,
                         T* __restrict__ hg, int l,
                         float* hl_s, float* hr_s, float* attnT, float* wa04_s) {
  const int bid = blockIdx.x;
  const int b = bid >> 2, hh = bid & 3;
  const int t = threadIdx.x;
  const int w = t >> 6, L = t & 63;

  const float* hlbase = hl + (size_t)(b * NS) * HD + hh * NF;
  const float* hrbase = hr + (size_t)(b * NS) * HD + hh * NF;

  // --- adjacency masks: all loads issued up-front, overlap staging ---
  unsigned mA = 0, mB = 0, mT = 0;
  #pragma unroll
  for (int p = 0; p < 9; ++p) {
    int ia = w + 8 * p, ib = ia + 4;
    if (ldv(adj, ia * NS + L) > 0.f) mA |= 1u << p;
    if (ldv(adj, ib * NS + L) > 0.f) mB |= 1u << p;
  }
  if (L < 16) {
    int isel0 = w + ((L < 8) ? 0 : 4);
    #pragma unroll
    for (int p = 0; p < 9; ++p) {
      if (ldv(adj, (isel0 + 8 * p) * NS + 64 + (L & 7)) > 0.f) mT |= 1u << p;
    }
  }

  // own-j hr row (j = L) -> registers
  const float4* hrg1 = (const float4*)(hrbase + L * HD);
  float4 hr1[16];
  #pragma unroll
  for (int q = 0; q < 16; ++q) hr1[q] = hrg1[q];

  if (t < NF) wa04_s[t] = 0.4f * ldv(Wa, l * HD + hh * NF + t);

  // stage hl and hr (all 72 rows)
  const float4* hlg4 = (const float4*)hlbase;
  const float4* hrg4 = (const float4*)hrbase;
  for (int c = t; c < NS * 16; c += 256) {
    int j = c >> 4, q = c & 15;
    *(float4*)&hl_s[j * SH + 4 * q] = hlg4[j * 64 + q];
    *(float4*)&hr_s[j * SH + 4 * q] = hrg4[j * 64 + q];
  }
  __syncthreads();

  // tail row j2 = 64+(L&7) hoisted into registers (loop-invariant)
  const int j2 = 64 + (L & 7);
  float4 h2r[16];
  #pragma unroll
  for (int q = 0; q < 16; ++q) h2r[q] = *(const float4*)&hr_s[j2 * SH + 4 * q];

  float B1 = 0.f, B2 = 0.f;
  #pragma unroll
  for (int q = 0; q < 16; ++q) {
    float4 w4 = *(const float4*)&wa04_s[4 * q];
    B1 = fmaf(w4.x, hr1[q].x, B1); B1 = fmaf(w4.y, hr1[q].y, B1);
    B1 = fmaf(w4.z, hr1[q].z, B1); B1 = fmaf(w4.w, hr1[q].w, B1);
    B2 = fmaf(w4.x, h2r[q].x, B2); B2 = fmaf(w4.y, h2r[q].y, B2);
    B2 = fmaf(w4.z, h2r[q].z, B2); B2 = fmaf(w4.w, h2r[q].w, B2);
  }
  float B15_1 = 1.5f * B1, B15_2 = 1.5f * B2;
  float wa04L = wa04_s[L];
  const bool selA = (L < 8);

  // score + softmax: 9 pairs per wave (ia = w+8p, ib = ia+4)
  for (int p = 0; p < 9; ++p) {
    int ia = w + 8 * p, ib = ia + 4;
    float ava = wa04L * hl_s[ia * SH + L];
    float avb = wa04L * hl_s[ib * SH + L];
    #pragma unroll
    for (int o = 32; o > 0; o >>= 1) { ava += __shfl_xor(ava, o); avb += __shfl_xor(avb, o); }
    float A15a = 1.5f * ava, A15b = 1.5f * avb;

    float acc1a = 0.f, acc1b = 0.f, acc2 = 0.f;
    #pragma unroll
    for (int q = 0; q < 16; ++q) {
      float4 w4 = *(const float4*)&wa04_s[4 * q];
      float4 ha = *(const float4*)&hl_s[ia * SH + 4 * q];
      float4 hb = *(const float4*)&hl_s[ib * SH + 4 * q];
      float4 h2 = h2r[q];
      float e;
      e = ha.x + hr1[q].x; acc1a = fmaf(w4.x, fabsf(e), acc1a);
      e = ha.y + hr1[q].y; acc1a = fmaf(w4.y, fabsf(e), acc1a);
      e = ha.z + hr1[q].z; acc1a = fmaf(w4.z, fabsf(e), acc1a);
      e = ha.w + hr1[q].w; acc1a = fmaf(w4.w, fabsf(e), acc1a);
      e = hb.x + hr1[q].x; acc1b = fmaf(w4.x, fabsf(e), acc1b);
      e = hb.y + hr1[q].y; acc1b = fmaf(w4.y, fabsf(e), acc1b);
      e = hb.z + hr1[q].z; acc1b = fmaf(w4.z, fabsf(e), acc1b);
      e = hb.w + hr1[q].w; acc1b = fmaf(w4.w, fabsf(e), acc1b);
      e = (selA ? ha.x : hb.x) + h2.x; acc2 = fmaf(w4.x, fabsf(e), acc2);
      e = (selA ? ha.y : hb.y) + h2.y; acc2 = fmaf(w4.y, fabsf(e), acc2);
      e = (selA ? ha.z : hb.z) + h2.z; acc2 = fmaf(w4.z, fabsf(e), acc2);
      e = (selA ? ha.w : hb.w) + h2.w; acc2 = fmaf(w4.w, fabsf(e), acc2);
    }
    float e1a = ((mA >> p) & 1u) ? __expf(A15a + B15_1 + acc1a) : 0.f;
    float e2a = (selA && ((mT >> p) & 1u)) ? __expf(A15a + B15_2 + acc2) : 0.f;
    float e1b = ((mB >> p) & 1u) ? __expf(A15b + B15_1 + acc1b) : 0.f;
    float e2b = (L >= 8 && L < 16 && ((mT >> p) & 1u)) ? __expf(A15b + B15_2 + acc2) : 0.f;
    float sea = e1a + e2a, seb = e1b + e2b;
    #pragma unroll
    for (int o = 32; o > 0; o >>= 1) { sea += __shfl_xor(sea, o); seb += __shfl_xor(seb, o); }
    float inva = 1.f / sea, invb = 1.f / seb;
    attnT[L * SA + ia] = e1a * inva;
    attnT[L * SA + ib] = e1b * invb;
    if (L < 8)            attnT[(64 + L) * SA + ia] = e2a * inva;
    if (L >= 8 && L < 16) attnT[(64 + (L & 7)) * SA + ib] = e2b * invb;
  }
  __syncthreads();

  // aggregation: out[i][f=L] = sum_j attnT[j][i] * hr_s[j][L], 18 groups of 4
  for (int p = 0; p < 5; ++p) {
    int g = w + 4 * p;
    if (g >= 18) break;
    int i0 = 4 * g;
    float a0 = 0.f, a1 = 0.f, a2 = 0.f, a3 = 0.f;
    #pragma unroll 4
    for (int j = 0; j < NS; ++j) {
      float4 at = *(const float4*)&attnT[j * SA + i0];
      float hv = hr_s[j * SH + L];
      a0 = fmaf(at.x, hv, a0); a1 = fmaf(at.y, hv, a1);
      a2 = fmaf(at.z, hv, a2); a3 = fmaf(at.w, hv, a3);
    }
    T* o = hg + (size_t)(b * NS + i0) * HD + hh * NF + L;
    stv(o, 0, a0); stv(o, HD, a1); stv(o, 2 * HD, a2); stv(o, 3 * HD, a3);
  }
}
__global__ void __launch_bounds__(256, 1) k_gat(const float* hl, const float* hr, const void* adj,
    const void* Wa, void* hg, int l, const int* flag) {
  __shared__ float hl_s[NS * SH];
  __shared__ float hr_s[NS * SH];
  __shared__ float attnT[NS * SA];
  __shared__ float wa04_s[NF];
  if (*flag) gat_body<bf16>(hl, hr, (const bf16*)adj, (const bf16*)Wa, (bf16*)hg, l, hl_s, hr_s, attnT, wa04_s);
  else gat_body<float>(hl, hr, (const float*)adj, (const float*)Wa, (float*)hg, l, hl_s, hr_s, attnT, wa04_s);
}

// ---------- op GEMM accumulate: x += hg @ op_W[l] + op_b[l]
__device__ void gemmop_scalar(const float* hg, const float* opW, const float* opb, float* x,
                              int l, float (*xs)[HD]) {
  int row0 = blockIdx.x * GROWS; int t = threadIdx.x;
  #pragma unroll
  for (int r = 0; r < GROWS; ++r) xs[r][t] = hg[(size_t)(row0 + r) * HD + t];
  __syncthreads();
  const float* W = opW + (size_t)l * HD * HD;
  float acc[GROWS];
  #pragma unroll
  for (int r = 0; r < GROWS; ++r) acc[r] = 0.f;
  for (int k = 0; k < HD; ++k) {
    float wv = W[k * HD + t];
    #pragma unroll
    for (int r = 0; r < GROWS; ++r) acc[r] += xs[r][k] * wv;
  }
  float bias = opb[l * HD + t];
  #pragma unroll
  for (int r = 0; r < GROWS; ++r) x[(size_t)(row0 + r) * HD + t] += acc[r] + bias;
}
__device__ void gemmop_mfma(const u16* hg_b, const u16* opWt, const u16* opb,
                            float* x, int l, int row0) {
  int t = threadIdx.x, w = t >> 6, ln = t & 63;
  int lr16 = ln & 15, lk = ln >> 4, c0 = w * 64;
  f32x4 acc[4] = {};
  mfma_accum(hg_b + (size_t)(row0 + lr16) * HD + lk * 8,
             opWt + (size_t)l * HD * HD + (size_t)(c0 + lr16) * HD + lk * 8, acc);
  int orow = row0 + lk * 4, ncol = c0 + lr16;
  float* xp = x + (size_t)orow * HD + ncol;
  #pragma unroll
  for (int f = 0; f < 4; ++f) {
    float bias = b2f(opb[l * HD + ncol + f * 16]);
    #pragma unroll
    for (int j = 0; j < 4; ++j)
      xp[j * HD + f * 16] += acc[f][j] + bias;
  }
}
// fp32 path, NO LDS: A-fragments read directly from global fp32 hg and hi/lo-split
// in registers (identical values + reduction order as the old LDS-staged variant).
__device__ void gemmop_mfma3_direct(const float* __restrict__ hg, const u16* __restrict__ opHi,
                                    const u16* __restrict__ opLo, const float* __restrict__ opb,
                                    float* __restrict__ x, int l, int row0) {
  int t = threadIdx.x, w = t >> 6, ln = t & 63;
  int lr16 = ln & 15, lk = ln >> 4, c0 = w * 64;
  const float* arow = hg + (size_t)(row0 + lr16) * HD + lk * 8;
  const u16* bhi = opHi + (size_t)l * HD * HD + (size_t)(c0 + lr16) * HD + lk * 8;
  const u16* blo = opLo + (size_t)l * HD * HD + (size_t)(c0 + lr16) * HD + lk * 8;
  f32x4 acc[4] = {};
  #pragma unroll
  for (int kk = 0; kk < 8; ++kk) {
    float4 f0 = *(const float4*)(arow + kk * 32);
    float4 f1 = *(const float4*)(arow + kk * 32 + 4);
    float v[8] = {f0.x, f0.y, f0.z, f0.w, f1.x, f1.y, f1.z, f1.w};
    union { u16 u[8]; bf16x8 v8; } ah, al;
    #pragma unroll
    for (int e = 0; e < 8; ++e) {
      u16 h = f2b(v[e]);
      ah.u[e] = h;
      al.u[e] = f2b(v[e] - b2f(h));
    }
    #pragma unroll
    for (int f = 0; f < 4; ++f) {
      bf16x8 bh = *(const bf16x8*)(bhi + (size_t)f * 16 * HD + kk * 32);
      bf16x8 bl = *(const bf16x8*)(blo + (size_t)f * 16 * HD + kk * 32);
      acc[f] = __builtin_amdgcn_mfma_f32_16x16x32_bf16(al.v8, bh, acc[f], 0, 0, 0);
      acc[f] = __builtin_amdgcn_mfma_f32_16x16x32_bf16(ah.v8, bl, acc[f], 0, 0, 0);
      acc[f] = __builtin_amdgcn_mfma_f32_16x16x32_bf16(ah.v8, bh, acc[f], 0, 0, 0);
    }
  }
  int orow = row0 + lk * 4, ncol = c0 + lr16;
  float* xp = x + (size_t)orow * HD + ncol;
  #pragma unroll
  for (int f = 0; f < 4; ++f) {
    float bias = opb[l * HD + ncol + f * 16];
    #pragma unroll
    for (int j = 0; j < 4; ++j)
      xp[j * HD + f * 16] += acc[f][j] + bias;
  }
}
__global__ void __launch_bounds__(256) k_gemm_op(const void* hg, const void* opW, const u16* opWt,
    const u16* opHi, const u16* opLo, const void* opb, float* x, int l,
    const int* flag, int wsok) {
  if (*flag) {
    if (blockIdx.x < (B * NS / 16))
      gemmop_mfma((const u16*)hg, opWt, (const u16*)opb, x, l, blockIdx.x * 16);
  } else if (wsok) {
    if (blockIdx.x < (B * NS / 16))
      gemmop_mfma3_direct((const float*)hg, opHi, opLo, (const float*)opb, x, l, blockIdx.x * 16);
  } else {
    __shared__ float xs[GROWS][HD];
    gemmop_scalar((const float*)hg, (const float*)opW, (const float*)opb, x, l, xs);
  }
}

// ---------- heads: 1024 threads/block, 4-way split on both the mean (s-axis) and GEMM (k-axis)
#define HTOT (NC + 3 + NS + NS + 128)   // 385
#define HPAD 392

template <typename T>
__device__ void heads_body(const float* x,
    const T* cardW, const T* cardb, const T* atW, const T* atb,
    const T* srcW, const T* srcb, const T* tgtW, const T* tgtb,
    const T* v1W, const T* v1b, const T* v2W, const T* v2b,
    T* out, float* spart, float* sge, float* hpart, float* sh1) {
  int b = blockIdx.x, t = threadIdx.x;
  int sq = t >> 8, tt = t & 255;
  float acc = 0.f;
  for (int ss = sq; ss < NS; ss += 4) acc += x[(size_t)(b * NS + ss) * HD + tt];
  spart[sq * HD + tt] = acc;
  __syncthreads();
  if (t < HD) sge[t] = (spart[t] + spart[HD + t] + spart[2 * HD + t] + spart[3 * HD + t]) * (1.f / NS);
  __syncthreads();
  #pragma unroll
  for (int pass = 0; pass < 2; ++pass) {
    int col = tt + pass * 256;
    if (col < HTOT) {
      const T* Wp; int stride, off;
      if (col < NC) { Wp = cardW; stride = NC; off = col; }
      else if (col < NC + 3) { Wp = atW; stride = 3; off = col - NC; }
      else if (col < NC + 3 + NS) { Wp = srcW; stride = NS; off = col - (NC + 3); }
      else if (col < NC + 3 + 2 * NS) { Wp = tgtW; stride = NS; off = col - (NC + 3 + NS); }
      else { Wp = v1W; stride = 128; off = col - (NC + 3 + 2 * NS); }
      const float* gp = sge + sq * 64;
      float p = 0.f;
      #pragma unroll 8
      for (int k = 0; k < 64; ++k) p += gp[k] * ldv(Wp, (sq * 64 + k) * stride + off);
      hpart[sq * HPAD + col] = p;
    }
  }
  __syncthreads();
  if (t < HTOT) {
    float v = hpart[t] + hpart[HPAD + t] + hpart[2 * HPAD + t] + hpart[3 * HPAD + t];
    if (t < NC) stv(out, b * NC + t, v + ldv(cardb, t));
    else if (t < NC + 3) stv(out, B * NC + b * 3 + (t - NC), v + ldv(atb, t - NC));
    else if (t < NC + 3 + NS) stv(out, B * NC + B * 3 + b * NS + (t - NC - 3), v + ldv(srcb, t - NC - 3));
    else if (t < NC + 3 + 2 * NS) stv(out, B * NC + B * 3 + B * NS + b * NS + (t - NC - 3 - NS), v + ldv(tgtb, t - NC - 3 - NS));
    else { int o = t - (NC + 3 + 2 * NS); sh1[o] = fmaxf(v + ldv(v1b, o), 0.f); }
  }
  __syncthreads();
  if (t < 64) {
    float pv = sh1[t] * ldv(v2W, t) + sh1[t + 64] * ldv(v2W, t + 64);
    #pragma unroll
    for (int o = 32; o > 0; o >>= 1) pv += __shfl_xor(pv, o);
    if (t == 0) stv(out, B * (NC + 3 + NS + NS) + b, tanhf(pv + ldv(v2b, 0)));
  }
}
__global__ void __launch_bounds__(1024) k_heads(const float* x,
    const void* cardW, const void* cardb, const void* atW, const void* atb,
    const void* srcW, const void* srcb, const void* tgtW, const void* tgtb,
    const void* v1W, const void* v1b, const void* v2W, const void* v2b,
    void* out, const int* flag) {
  __shared__ float spart[4 * HD];
  __shared__ float sge[HD];
  __shared__ float hpart[4 * HPAD];
  __shared__ float sh1[128];
  if (*flag) heads_body<bf16>(x, (const bf16*)cardW, (const bf16*)cardb, (const bf16*)atW,
                              (const bf16*)atb, (const bf16*)srcW, (const bf16*)srcb,
                              (const bf16*)tgtW, (const bf16*)tgtb, (const bf16*)v1W,
                              (const bf16*)v1b, (const bf16*)v2W, (const bf16*)v2b,
                              (bf16*)out, spart, sge, hpart, sh1);
  else heads_body<float>(x, (const float*)cardW, (const float*)cardb, (const float*)atW,
                         (const float*)atb, (const float*)srcW, (const float*)srcb,
                         (const float*)tgtW, (const float*)tgtb, (const float*)v1W,
                         (const float*)v1b, (const float*)v2W, (const float*)v2b,
                         (float*)out, spart, sge, hpart, sh1);
}

extern "C" void kernel_launch(void* const* d_in, const int* in_sizes, int n_in,
                              void* d_out, int out_size, void* d_ws, size_t ws_size,
                              hipStream_t stream) {
  const void* spatial = d_in[0];
  const void* cardctx = d_in[1];
  const void* adj = d_in[2];
  const void* ctxW = d_in[3]; const void* ctxb = d_in[4];
  const void* lncs = d_in[5]; const void* lncb = d_in[6];
  const void* inW = d_in[7];  const void* inb = d_in[8];
  const void* lnps = d_in[9]; const void* lnpb = d_in[10];
  const void* cpW = d_in[11]; const void* cpb = d_in[12];
  const void* Wl = d_in[13];  const void* Wr = d_in[14]; const void* Wa = d_in[15];
  const void* opW = d_in[16]; const void* opb = d_in[17];
  const void* cardW = d_in[18]; const void* cardb = d_in[19];
  const void* atW = d_in[20];   const void* atb = d_in[21];
  const void* srcW = d_in[22];  const void* srcb = d_in[23];
  const void* tgtW = d_in[24];  const void* tgtb = d_in[25];
  const void* v1W = d_in[26];   const void* v1b = d_in[27];
  const void* v2W = d_in[28];   const void* v2b = d_in[29];

  int* flag = (int*)d_ws;
  float* fb = (float*)((char*)d_ws + 256);
  float* g     = fb;                               // B*HD
  float* c_all = g + B * HD;                       // NL*B*HD
  float* x     = c_all + NL * B * HD;              // B*NS*HD
  float* hgf   = x + (size_t)B * NS * HD;          // B*NS*HD
  float* hl    = hgf + (size_t)B * NS * HD;        // B*NS*HD
  float* hr    = hl + (size_t)B * NS * HD;         // B*NS*HD

  // Base footprint (Round-2-proven): 256 + 4,800,512 floats = 18.32 MB.
  size_t base_bytes = 256 + ((size_t)B * HD + (size_t)NL * B * HD + 4 * (size_t)B * NS * HD) * 4;
  // Pool: max(bf16-mode: g_b + 4 transposed bf16 weights = 2.13 MB,
  //           fp32-mode: 6 hi/lo transposed bf16 weights  = 3.00 MB)
  size_t pool_b16 = ((size_t)B * HD + 4 * (size_t)NL * HD * HD) * 2;
  size_t pool_f32 = (size_t)6 * NL * HD * HD * 2;
  size_t pool_bytes = pool_f32 > pool_b16 ? pool_f32 : pool_b16;
  int wsok = (ws_size >= base_bytes + pool_bytes) ? 1 : 0;

  // If ws is generous: pool appended past base. Otherwise: fall back to the exact
  // Round-2 layout (pool aliased in hgf's upper half; fp32 path runs scalar).
  u16* pool = wsok ? (u16*)((char*)d_ws + base_bytes)
                   : (u16*)(hgf + (size_t)B * NS * HD / 2);
  // bf16-input mode pointers
  u16* g_b  = pool;
  u16* Wlt  = g_b + B * HD;
  u16* Wrt  = Wlt + NL * HD * HD;
  u16* opWt = Wrt + NL * HD * HD;
  u16* cpWt = opWt + NL * HD * HD;
  // fp32-input mode pointers (alias the same pool; modes are mutually exclusive)
  u16* WlHi = pool;              u16* WlLo = WlHi + NL * HD * HD;
  u16* WrHi = WlLo + NL * HD * HD; u16* WrLo = WrHi + NL * HD * HD;
  u16* opHi = WrLo + NL * HD * HD; u16* opLo = opHi + NL * HD * HD;

  k_detect<<<1, 64, 0, stream>>>(adj, flag);
  k_prep<<<256, 256, 0, stream>>>(Wl, Wr, opW, cpW, Wlt, Wrt, opWt, cpWt, flag);
  if (wsok)
    k_prep32<<<192, 256, 0, stream>>>(Wl, Wr, opW, WlHi, WlLo, WrHi, WrLo, opHi, opLo, flag);
  k_ctx<<<B, HD, 0, stream>>>(cardctx, ctxW, ctxb, lncs, lncb, g, g_b, flag);
  k_inproj<<<B * NS, HD, 0, stream>>>(spatial, inW, inb, x, flag);
  k_cproj_all<<<B * NL, HD, 0, stream>>>(g, g_b, cpW, cpWt, cpb, c_all, flag);
  for (int l = 0; l < NL; ++l) {
    k_lngemm_lr<<<B * NS / GROWS, 256, 0, stream>>>(x, c_all, lnps, lnpb, Wl, Wr, Wlt, Wrt,
                                                    WlHi, WlLo, WrHi, WrLo, hl, hr, l, flag, wsok);
    k_gat<<<B * NH, 256, 0, stream>>>(hl, hr, adj, Wa, hgf, l, flag);
    k_gemm_op<<<B * NS / GROWS, 256, 0, stream>>>(hgf, opW, opWt, opHi, opLo, opb, x, l, flag, wsok);
  }
  k_heads<<<B, 1024, 0, stream>>>(x, cardW, cardb, atW, atb, srcW, srcb, tgtW, tgtb,
                                  v1W, v1b, v2W, v2b, d_out, flag);
}